// Round 4
// baseline (260.168 us; speedup 1.0000x reference)
//
#include <hip/hip_runtime.h>
#include <hip/hip_bf16.h>
#include <stdint.h>

// Problem constants
#define TOKS   262144      // B*S = 32*8192
#define NGRP   16384       // B*G = 32*512
#define EMB    1024
#define HD     64

using bf16x8 = __attribute__((ext_vector_type(8))) short;   // 8 bf16 (4 VGPRs) MFMA operand
using f32x4  = __attribute__((ext_vector_type(4))) float;   // MFMA accumulator

__device__ __forceinline__ unsigned pack2(float a, float b) {
    union { __hip_bfloat162 h; unsigned u; } cvt;
    cvt.h = __float22bfloat162_rn(make_float2(a, b));   // RNE pk-convert
    return cvt.u;
}
__device__ __forceinline__ bf16x8 cvt8(float4 v0, float4 v1) {
    uint4 u;
    u.x = pack2(v0.x, v0.y);
    u.y = pack2(v0.z, v0.w);
    u.z = pack2(v1.x, v1.y);
    u.w = pack2(v1.z, v1.w);
    return __builtin_bit_cast(bf16x8, u);
}
__device__ __forceinline__ void gload_lds16(const unsigned short* g, unsigned short* l) {
    __builtin_amdgcn_global_load_lds(
        (const __attribute__((address_space(1))) void*)g,
        (__attribute__((address_space(3))) void*)l,
        16, 0, 0);
}

// ---------------------------------------------------------------------------
// K0: pack Wo (fp32 [1024][1024]) into MFMA-fragment-linear bf16 (blocks 0..511):
//       packed[((c*64 + nb)*64 + l)*8 + e] = bf16(Wo[nb*16 + (l&15)][c*32 + (l>>4)*8 + e])
//     Wq|Wk|Wv (fp32 [64][64]) -> bf16 packed [3][4096] (blocks 512..523).
// (Restored as its own kernel: round-3's fusion into k_fused cost ~20us.)
// ---------------------------------------------------------------------------
__global__ __launch_bounds__(256) void k_cvt(const float* __restrict__ wo,
                                             const float* __restrict__ wq,
                                             const float* __restrict__ wk,
                                             const float* __restrict__ wv,
                                             unsigned short* __restrict__ wob,
                                             unsigned short* __restrict__ wqkvb) {
    int bid = blockIdx.x;
    if (bid < 512) {
        int tid = bid * 256 + threadIdx.x;   // 0..131071, 8 elems each
        int c   = tid >> 12;                 // k-chunk of 32, 0..31
        int nb  = (tid >> 6) & 63;           // n-block of 16
        int l   = tid & 63;                  // lane within fragment
        int n   = nb * 16 + (l & 15);
        int k   = c * 32 + (l >> 4) * 8;
        const float* src = wo + (size_t)n * 1024 + k;
        float4 v0 = *(const float4*)(src);
        float4 v1 = *(const float4*)(src + 4);
        *(bf16x8*)(wob + (size_t)tid * 8) = cvt8(v0, v1);
    } else {
        int b = bid - 512;                  // 0..11
        int m = b >> 2;
        const float* src = (m == 0) ? wq : ((m == 1) ? wk : wv);
        int idx = ((b & 3) * 256 + threadIdx.x) * 4;
        float4 v = *(const float4*)(src + idx);
        uint2 p;
        p.x = pack2(v.x, v.y);
        p.y = pack2(v.z, v.w);
        *(uint2*)(wqkvb + m * 4096 + idx) = p;
    }
}

// ---------------------------------------------------------------------------
// K1: FUSED QKV projection + 16x16 attention, MFMA throughout.
// Round-4 change: the wave's 2 groups are processed SEQUENTIALLY (was
// interleaved). Rocprof (round 3) showed k_fused is latency-bound with
// nothing busy (Mfma 4.6%, VALU 18%, HBM 14%) and occupancy capped at
// ~2.75 blocks/CU by 36.9KB LDS. Sequential groups halve LDS to 18.4KB
// -> 8 blocks/CU (grid is exactly 8/CU), launch_bounds(256,8) pins
// VGPR<=64 -> up to 32 waves/CU. TLP replaces the lost intra-wave ILP.
// Per-wave-private LDS, no barriers. W pre-converted bf16 (k_cvt).
// ---------------------------------------------------------------------------
#define SCL 0.0450842200278f   /* log2(e)/32 */

__global__ __launch_bounds__(256, 8) void k_fused(const float* __restrict__ x,
                                                  const unsigned short* __restrict__ wqkv,
                                                  unsigned short* __restrict__ out2) {
    // [wave][Q/K][16 x 72 bf16]  (pad 64->72 breaks bank aliasing)
    __shared__ __align__(16) unsigned short qkls[4][2][16 * 72];
    int t = threadIdx.x;
    int w = t >> 6, l = t & 63;
    int c = l & 15, q = l >> 4;
    int waveTok0 = blockIdx.x * 128 + w * 32;

    #pragma unroll 1
    for (int g = 0; g < 2; ++g) {
        // ---- x A-frags (fp32 -> bf16 in-register) ----
        bf16x8 xa[2];
        {
            const float* xp = x + (size_t)(waveTok0 + g * 16 + c) * 64 + q * 8;
            #pragma unroll
            for (int kc = 0; kc < 2; ++kc) {
                float4 v0 = *(const float4*)(xp + kc * 32);
                float4 v1 = *(const float4*)(xp + kc * 32 + 4);
                xa[kc] = cvt8(v0, v1);
            }
        }

        // ---- projections: Q,K -> LDS tiles; V stays in regs ----
        uint2 pkV[4];
        #pragma unroll
        for (int m = 0; m < 3; ++m) {
            #pragma unroll
            for (int nb = 0; nb < 4; ++nb) {
                const unsigned short* wp = wqkv + m * 4096 + (nb * 16 + c) * 64 + q * 8;
                bf16x8 w0 = *(const bf16x8*)(wp);
                bf16x8 w1 = *(const bf16x8*)(wp + 32);
                f32x4 acc = (f32x4){0.f, 0.f, 0.f, 0.f};
                acc = __builtin_amdgcn_mfma_f32_16x16x32_bf16(xa[0], w0, acc, 0, 0, 0);
                acc = __builtin_amdgcn_mfma_f32_16x16x32_bf16(xa[1], w1, acc, 0, 0, 0);
                unsigned u01 = pack2(acc[0], acc[1]);
                unsigned u23 = pack2(acc[2], acc[3]);
                if (m < 2) {
                    unsigned short* tile = qkls[w][m];
                    int base = 4 * q * 72 + nb * 16 + c;
                    tile[base]       = (unsigned short)u01;
                    tile[base + 72]  = (unsigned short)(u01 >> 16);
                    tile[base + 144] = (unsigned short)u23;
                    tile[base + 216] = (unsigned short)(u23 >> 16);
                } else {
                    pkV[nb].x = u01;    // tokens 4q+0,1
                    pkV[nb].y = u23;    // tokens 4q+2,3
                }
            }
        }

        // ---- energy^T[j][i]: A = K-frag, B = Q-frag ----
        f32x4 e = (f32x4){0.f, 0.f, 0.f, 0.f};
        {
            const unsigned short* Qt = qkls[w][0];
            const unsigned short* Kt = qkls[w][1];
            #pragma unroll
            for (int kc = 0; kc < 2; ++kc) {
                bf16x8 ka = *(const bf16x8*)(Kt + c * 72 + kc * 32 + q * 8);
                bf16x8 qb = *(const bf16x8*)(Qt + c * 72 + kc * 32 + q * 8);
                e = __builtin_amdgcn_mfma_f32_16x16x32_bf16(ka, qb, e, 0, 0, 0);
            }
        }
        // lane(q,c): e[r] = energy[i=c][j=4q+r]

        // ---- softmax over j ----
        unsigned pa0, pa1;
        {
            float mx = fmaxf(fmaxf(e[0], e[1]), fmaxf(e[2], e[3]));
            mx = fmaxf(mx, __shfl_xor(mx, 16));
            mx = fmaxf(mx, __shfl_xor(mx, 32));
            float p0 = exp2f((e[0] - mx) * SCL);
            float p1 = exp2f((e[1] - mx) * SCL);
            float p2 = exp2f((e[2] - mx) * SCL);
            float p3 = exp2f((e[3] - mx) * SCL);
            float s = p0 + p1 + p2 + p3;
            s += __shfl_xor(s, 16);
            s += __shfl_xor(s, 32);
            float rinv = 1.0f / s;
            pa0 = pack2(p0 * rinv, p1 * rinv);   // j = 4q+0,1
            pa1 = pack2(p2 * rinv, p3 * rinv);   // j = 4q+2,3
        }

        // ---- PV ----
        int s0 = (32 * q + c) & 63;
        int s1 = (32 * q + 16 + c) & 63;
        int v0 = 32 * (q & 1) + c;
        int v1 = v0 + 16;
        bool hi = (q >= 2);                 // k >= 16 -> zero pad
        {
            int a0 = __shfl((int)pa0, s0);
            int a1 = __shfl((int)pa1, s0);
            int a2 = __shfl((int)pa0, s1);
            int a3 = __shfl((int)pa1, s1);
            uint4 A2u;
            A2u.x = hi ? 0u : (unsigned)a0;
            A2u.y = hi ? 0u : (unsigned)a1;
            A2u.z = hi ? 0u : (unsigned)a2;
            A2u.w = hi ? 0u : (unsigned)a3;
            bf16x8 A2 = __builtin_bit_cast(bf16x8, A2u);

            unsigned short* Ot = qkls[w][0];   // Q tile done being read
            #pragma unroll
            for (int nb = 0; nb < 4; ++nb) {
                uint4 B2u;
                B2u.x = (unsigned)__shfl((int)pkV[nb].x, v0);
                B2u.y = (unsigned)__shfl((int)pkV[nb].y, v0);
                B2u.z = (unsigned)__shfl((int)pkV[nb].x, v1);
                B2u.w = (unsigned)__shfl((int)pkV[nb].y, v1);
                bf16x8 B2 = __builtin_bit_cast(bf16x8, B2u);
                f32x4 o = (f32x4){0.f, 0.f, 0.f, 0.f};
                o = __builtin_amdgcn_mfma_f32_16x16x32_bf16(A2, B2, o, 0, 0, 0);
                unsigned u01 = pack2(o[0], o[1]);
                unsigned u23 = pack2(o[2], o[3]);
                int base = 4 * q * 72 + nb * 16 + c;
                Ot[base]       = (unsigned short)u01;
                Ot[base + 72]  = (unsigned short)(u01 >> 16);
                Ot[base + 144] = (unsigned short)u23;
                Ot[base + 216] = (unsigned short)(u23 >> 16);
            }
        }

        // ---- coalesced stores: lane l covers row l>>2, 16 cols ----
        {
            int gi = (waveTok0 >> 4) + g;
            int b    = gi >> 9;
            int grem = gi & 511;
            int rowbase = b * 512 + (grem >> 4);
            int colpref = (grem & 15) * 64;
            const unsigned short* osrc = qkls[w][0] + (l >> 2) * 72 + (l & 3) * 16;
            uint4 ov0 = *(const uint4*)(osrc);
            uint4 ov1 = *(const uint4*)(osrc + 8);
            unsigned short* dst = out2 + (size_t)(rowbase + (l >> 2) * 32) * 1024
                                       + colpref + (l & 3) * 16;
            *(uint4*)(dst)     = ov0;
            *(uint4*)(dst + 8) = ov1;
        }
    }
}

// ---------------------------------------------------------------------------
// K2: C[16384][1024] = out2 @ Wo^T + bo  (bf16 MFMA, fp32 acc/out)
// 256x256 tile, BK=64, 512 threads (8 waves, 2Mx4N). One barrier per K-tile;
// waves free-run within a tile so LDS reads of one wave overlap MFMAs of
// another. B = Wo pre-packed fragment-linear (one coalesced 16B/lane L2 load
// per frag, no LDS); A triple-buffered LDS staged 2 tiles ahead via
// global_load_lds; counted vmcnt(4) keeps the A prefetch in flight.
// ---------------------------------------------------------------------------
#define STG(gb, lb, half, kt) do { \
    gload_lds16((gb) + (size_t)(half) * 131072 + (size_t)(kt) * 64 + ga0, \
                (lb) + (half) * 8192 + lo0); \
    gload_lds16((gb) + (size_t)(half) * 131072 + (size_t)(kt) * 64 + ga1, \
                (lb) + (half) * 8192 + lo1); \
} while (0)

#define LDA4(buf, mh) do { \
    _Pragma("unroll") \
    for (int i2 = 0; i2 < 4; ++i2) { \
        const unsigned short* _p = (buf) + (wrow + ((mh) * 4 + i2) * 16 + lm) * 64; \
        a[i2][0] = *(const bf16x8*)(_p + jo0); \
        a[i2][1] = *(const bf16x8*)(_p + jo1); \
    } \
} while (0)

// next tile's B-frags: 8 x global dwordx4, 16B/lane, L2-hot
#define GLBB(d, gp) do { \
    _Pragma("unroll") \
    for (int n = 0; n < 4; ++n) { \
        d[n][0] = *(const bf16x8*)((gp) + n * 512); \
        d[n][1] = *(const bf16x8*)((gp) + 32768 + n * 512); \
    } \
} while (0)

// 32 MFMAs: one M-half (4 row-frags) x full N (4 col-frags) x K=64 (2 chained)
#define MM16(mh, B) do { \
    _Pragma("unroll") \
    for (int i2 = 0; i2 < 4; ++i2) { \
        _Pragma("unroll") \
        for (int n = 0; n < 4; ++n) { \
            acc[(mh)*4+i2][n] = __builtin_amdgcn_mfma_f32_16x16x32_bf16( \
                a[i2][0], B[n][0], acc[(mh)*4+i2][n], 0, 0, 0); \
            acc[(mh)*4+i2][n] = __builtin_amdgcn_mfma_f32_16x16x32_bf16( \
                a[i2][1], B[n][1], acc[(mh)*4+i2][n], 0, 0, 0); \
        } \
    } \
} while (0)

#define TILE(_t, cB, nB) do { \
    if ((_t) < 15) GLBB(nB, gB); \
    if ((_t) < 14) { STG(Ab, pAs, 0, (_t) + 2); STG(Ab, pAs, 1, (_t) + 2); } \
    LDA4(pAr, 0); \
    asm volatile("s_waitcnt lgkmcnt(0)" ::: "memory"); \
    __builtin_amdgcn_sched_barrier(0); \
    __builtin_amdgcn_s_setprio(1); \
    MM16(0, cB); \
    __builtin_amdgcn_s_setprio(0); \
    LDA4(pAr, 1); \
    asm volatile("s_waitcnt lgkmcnt(0)" ::: "memory"); \
    __builtin_amdgcn_sched_barrier(0); \
    __builtin_amdgcn_s_setprio(1); \
    MM16(1, cB); \
    __builtin_amdgcn_s_setprio(0); \
    if ((_t) < 14)       { asm volatile("s_waitcnt vmcnt(4)" ::: "memory"); } \
    else if ((_t) == 14) { asm volatile("s_waitcnt vmcnt(0)" ::: "memory"); } \
    __builtin_amdgcn_s_barrier(); \
    { unsigned short* _tmp = pAr; pAr = pAn; pAn = pAs; pAs = _tmp; } \
    gB += 65536; \
} while (0)

__global__ __launch_bounds__(512, 2) void k_gemm256(const unsigned short* __restrict__ A,
                                                    const unsigned short* __restrict__ Bp,
                                                    const float* __restrict__ bias,
                                                    float* __restrict__ C) {
    extern __shared__ __align__(16) unsigned short lds[];
    unsigned short* As0 = lds;                 // [256][64] bf16
    unsigned short* As1 = lds + 16384;
    unsigned short* As2 = lds + 32768;         // 96 KiB total, A only

    const int t = threadIdx.x;
    const int w = t >> 6, l = t & 63;
    const int lm = l & 15, q4 = l >> 4;
    const int jxor = lm & 7;
    const int jo0 = ((0 + q4) ^ jxor) * 8;     // kc=0 chunk (swizzled)
    const int jo1 = ((4 + q4) ^ jxor) * 8;     // kc=1 chunk (swizzled)

    // bijective XCD swizzle (nwg = 256, divisible by 8)
    const int bid = blockIdx.x;
    const int wg  = (bid & 7) * 32 + (bid >> 3);
    const int m0  = (wg >> 2) * 256;
    const int n0  = (wg & 3) * 256;

    const int wrow = (w >> 2) * 128;           // wave's M offset in tile
    const int wcol = (w & 3) * 64;             // wave's N offset in tile

    // A staging slots: s = w*128 + {l, l+64} cover 1024 x 16B chunks/half-tile
    const int s1 = w * 128 + l;
    const int s2 = s1 + 64;
    const int r0 = s1 >> 3, c0 = s1 & 7;
    const int r1 = s2 >> 3, c1 = s2 & 7;
    const size_t ga0 = (size_t)r0 * 1024 + (size_t)((c0 ^ (r0 & 7)) * 8);
    const size_t ga1 = (size_t)r1 * 1024 + (size_t)((c1 ^ (r1 & 7)) * 8);
    const int lo0 = s1 * 8;
    const int lo1 = s2 * 8;

    const unsigned short* Ab = A + (size_t)m0 * 1024;
    // fragment-linear B base: this wave's 4 n-blocks, this lane's 16B
    const unsigned short* gB = Bp + (size_t)((n0 >> 4) + (wcol >> 4)) * 512
                                  + (size_t)l * 8;

    f32x4 acc[8][4];
    #pragma unroll
    for (int mi = 0; mi < 8; ++mi)
        #pragma unroll
        for (int ni = 0; ni < 4; ++ni)
            acc[mi][ni] = (f32x4){0.f, 0.f, 0.f, 0.f};

    unsigned short* pAr = As0;   // A(t)   read
    unsigned short* pAn = As1;   // A(t+1)
    unsigned short* pAs = As2;   // A(t+2) stage target

    bf16x8 a[4][2];
    bf16x8 bC[4][2], bN[4][2];

    // ---- prologue: B(0) first (oldest), then A0, A1 ----
    GLBB(bC, gB);
    STG(Ab, pAr, 0, 0); STG(Ab, pAr, 1, 0);
    STG(Ab, pAn, 0, 1); STG(Ab, pAn, 1, 1);
    asm volatile("s_waitcnt vmcnt(4)" ::: "memory");   // B0 + A0 landed, A1 in flight
    __builtin_amdgcn_s_barrier();
    gB += 65536;                                        // point at tile 1

    #pragma unroll 1
    for (int tt = 0; tt < 8; ++tt) {
        TILE(2 * tt,     bC, bN);
        TILE(2 * tt + 1, bN, bC);
    }

    // ---- epilogue: bias + fp32 stores, 4 consecutive 64B bursts per (mi,r)
    float bc[4];
    #pragma unroll
    for (int ni = 0; ni < 4; ++ni) bc[ni] = bias[n0 + wcol + ni * 16 + lm];
    #pragma unroll
    for (int mi = 0; mi < 8; ++mi) {
        #pragma unroll
        for (int r = 0; r < 4; ++r) {
            const int row = m0 + wrow + mi * 16 + q4 * 4 + r;
            float* cp = C + (size_t)row * 1024 + n0 + wcol + lm;
            #pragma unroll
            for (int ni = 0; ni < 4; ++ni)
                cp[ni * 16] = acc[mi][ni][r] + bc[ni];
        }
    }
}

// ---------------------------------------------------------------------------
extern "C" void kernel_launch(void* const* d_in, const int* in_sizes, int n_in,
                              void* d_out, int out_size, void* d_ws, size_t ws_size,
                              hipStream_t stream) {
    const float* x  = (const float*)d_in[0];
    const float* wq = (const float*)d_in[1];
    const float* wk = (const float*)d_in[2];
    const float* wv = (const float*)d_in[3];
    const float* wo = (const float*)d_in[4];
    const float* bo = (const float*)d_in[5];
    float* out = (float*)d_out;

    unsigned short* out2  = (unsigned short*)d_ws;           // 16384*1024 bf16 (32 MB)
    unsigned short* wob   = out2 + (size_t)NGRP * 1024;      // 1024*1024 bf16 packed (2 MB)
    unsigned short* wqkvb = wob + (size_t)EMB * EMB;         // 3*4096 bf16 (24 KB)

    static int s_once = []() {
        hipFuncSetAttribute((const void*)k_gemm256,
                            hipFuncAttributeMaxDynamicSharedMemorySize, 98304);
        return 0;
    }();
    (void)s_once;

    k_cvt    <<<524,  256, 0, stream>>>(wo, wq, wk, wv, wob, wqkvb);
    k_fused  <<<2048, 256, 0, stream>>>(x, wqkvb, out2);
    k_gemm256<<<256, 512, 98304, stream>>>(out2, wob, bo, out);
}

// Round 5
// 186.112 us; speedup vs baseline: 1.3979x; 1.3979x over previous
//
#include <hip/hip_runtime.h>
#include <hip/hip_bf16.h>
#include <stdint.h>

// Problem constants
#define TOKS   262144      // B*S = 32*8192
#define NGRP   16384       // B*G = 32*512
#define EMB    1024
#define HD     64

using bf16x8 = __attribute__((ext_vector_type(8))) short;   // 8 bf16 (4 VGPRs) MFMA operand
using f32x4  = __attribute__((ext_vector_type(4))) float;   // MFMA accumulator

__device__ __forceinline__ unsigned pack2(float a, float b) {
    union { __hip_bfloat162 h; unsigned u; } cvt;
    cvt.h = __float22bfloat162_rn(make_float2(a, b));   // RNE pk-convert
    return cvt.u;
}
__device__ __forceinline__ bf16x8 cvt8(float4 v0, float4 v1) {
    uint4 u;
    u.x = pack2(v0.x, v0.y);
    u.y = pack2(v0.z, v0.w);
    u.z = pack2(v1.x, v1.y);
    u.w = pack2(v1.z, v1.w);
    return __builtin_bit_cast(bf16x8, u);
}
__device__ __forceinline__ void gload_lds16(const unsigned short* g, unsigned short* l) {
    __builtin_amdgcn_global_load_lds(
        (const __attribute__((address_space(1))) void*)g,
        (__attribute__((address_space(3))) void*)l,
        16, 0, 0);
}

// ---------------------------------------------------------------------------
// K0: pack Wo (fp32 [1024][1024]) into MFMA-fragment-linear bf16 (blocks 0..511):
//       packed[((c*64 + nb)*64 + l)*8 + e] = bf16(Wo[nb*16 + (l&15)][c*32 + (l>>4)*8 + e])
//     Wq|Wk|Wv (fp32 [64][64]) -> bf16 packed [3][4096] (blocks 512..523).
// ---------------------------------------------------------------------------
__global__ __launch_bounds__(256) void k_cvt(const float* __restrict__ wo,
                                             const float* __restrict__ wq,
                                             const float* __restrict__ wk,
                                             const float* __restrict__ wv,
                                             unsigned short* __restrict__ wob,
                                             unsigned short* __restrict__ wqkvb) {
    int bid = blockIdx.x;
    if (bid < 512) {
        int tid = bid * 256 + threadIdx.x;   // 0..131071, 8 elems each
        int c   = tid >> 12;                 // k-chunk of 32, 0..31
        int nb  = (tid >> 6) & 63;           // n-block of 16
        int l   = tid & 63;                  // lane within fragment
        int n   = nb * 16 + (l & 15);
        int k   = c * 32 + (l >> 4) * 8;
        const float* src = wo + (size_t)n * 1024 + k;
        float4 v0 = *(const float4*)(src);
        float4 v1 = *(const float4*)(src + 4);
        *(bf16x8*)(wob + (size_t)tid * 8) = cvt8(v0, v1);
    } else {
        int b = bid - 512;                  // 0..11
        int m = b >> 2;
        const float* src = (m == 0) ? wq : ((m == 1) ? wk : wv);
        int idx = ((b & 3) * 256 + threadIdx.x) * 4;
        float4 v = *(const float4*)(src + idx);
        uint2 p;
        p.x = pack2(v.x, v.y);
        p.y = pack2(v.z, v.w);
        *(uint2*)(wqkvb + m * 4096 + idx) = p;
    }
}

// ---------------------------------------------------------------------------
// K1: FUSED QKV projection + 16x16 attention, MFMA throughout.
// Sequential groups (round 4, correctness-verified): LDS 18.4 KB/block ->
// 8 blocks/CU possible. Round-4's __launch_bounds__(256,8) pin strangled the
// allocator to 32 VGPR -> ~280 MB of scratch spills per dispatch (FETCH/WRITE
// 175/176 MB, dur 125us). Fix: plain __launch_bounds__(256); sequential
// groups have fewer live values than the 60-VGPR interleaved variant, so
// natural allocation should land <=64 VGPR -> 8 waves/SIMD by VGPR, 8
// blocks/CU by LDS (grid = 2048 = 8 x 256 CUs exactly).
// Per-wave-private LDS, no barriers. W pre-converted bf16 (k_cvt).
// ---------------------------------------------------------------------------
#define SCL 0.0450842200278f   /* log2(e)/32 */

__global__ __launch_bounds__(256) void k_fused(const float* __restrict__ x,
                                               const unsigned short* __restrict__ wqkv,
                                               unsigned short* __restrict__ out2) {
    // [wave][Q/K][16 x 72 bf16]  (pad 64->72 breaks bank aliasing)
    __shared__ __align__(16) unsigned short qkls[4][2][16 * 72];
    int t = threadIdx.x;
    int w = t >> 6, l = t & 63;
    int c = l & 15, q = l >> 4;
    int waveTok0 = blockIdx.x * 128 + w * 32;

    #pragma unroll 1
    for (int g = 0; g < 2; ++g) {
        // ---- x A-frags (fp32 -> bf16 in-register) ----
        bf16x8 xa[2];
        {
            const float* xp = x + (size_t)(waveTok0 + g * 16 + c) * 64 + q * 8;
            #pragma unroll
            for (int kc = 0; kc < 2; ++kc) {
                float4 v0 = *(const float4*)(xp + kc * 32);
                float4 v1 = *(const float4*)(xp + kc * 32 + 4);
                xa[kc] = cvt8(v0, v1);
            }
        }

        // ---- projections: Q,K -> LDS tiles; V stays in regs ----
        uint2 pkV[4];
        #pragma unroll
        for (int m = 0; m < 3; ++m) {
            #pragma unroll
            for (int nb = 0; nb < 4; ++nb) {
                const unsigned short* wp = wqkv + m * 4096 + (nb * 16 + c) * 64 + q * 8;
                bf16x8 w0 = *(const bf16x8*)(wp);
                bf16x8 w1 = *(const bf16x8*)(wp + 32);
                f32x4 acc = (f32x4){0.f, 0.f, 0.f, 0.f};
                acc = __builtin_amdgcn_mfma_f32_16x16x32_bf16(xa[0], w0, acc, 0, 0, 0);
                acc = __builtin_amdgcn_mfma_f32_16x16x32_bf16(xa[1], w1, acc, 0, 0, 0);
                unsigned u01 = pack2(acc[0], acc[1]);
                unsigned u23 = pack2(acc[2], acc[3]);
                if (m < 2) {
                    unsigned short* tile = qkls[w][m];
                    int base = 4 * q * 72 + nb * 16 + c;
                    tile[base]       = (unsigned short)u01;
                    tile[base + 72]  = (unsigned short)(u01 >> 16);
                    tile[base + 144] = (unsigned short)u23;
                    tile[base + 216] = (unsigned short)(u23 >> 16);
                } else {
                    pkV[nb].x = u01;    // tokens 4q+0,1
                    pkV[nb].y = u23;    // tokens 4q+2,3
                }
            }
        }

        // ---- energy^T[j][i]: A = K-frag, B = Q-frag ----
        f32x4 e = (f32x4){0.f, 0.f, 0.f, 0.f};
        {
            const unsigned short* Qt = qkls[w][0];
            const unsigned short* Kt = qkls[w][1];
            #pragma unroll
            for (int kc = 0; kc < 2; ++kc) {
                bf16x8 ka = *(const bf16x8*)(Kt + c * 72 + kc * 32 + q * 8);
                bf16x8 qb = *(const bf16x8*)(Qt + c * 72 + kc * 32 + q * 8);
                e = __builtin_amdgcn_mfma_f32_16x16x32_bf16(ka, qb, e, 0, 0, 0);
            }
        }
        // lane(q,c): e[r] = energy[i=c][j=4q+r]

        // ---- softmax over j ----
        unsigned pa0, pa1;
        {
            float mx = fmaxf(fmaxf(e[0], e[1]), fmaxf(e[2], e[3]));
            mx = fmaxf(mx, __shfl_xor(mx, 16));
            mx = fmaxf(mx, __shfl_xor(mx, 32));
            float p0 = exp2f((e[0] - mx) * SCL);
            float p1 = exp2f((e[1] - mx) * SCL);
            float p2 = exp2f((e[2] - mx) * SCL);
            float p3 = exp2f((e[3] - mx) * SCL);
            float s = p0 + p1 + p2 + p3;
            s += __shfl_xor(s, 16);
            s += __shfl_xor(s, 32);
            float rinv = 1.0f / s;
            pa0 = pack2(p0 * rinv, p1 * rinv);   // j = 4q+0,1
            pa1 = pack2(p2 * rinv, p3 * rinv);   // j = 4q+2,3
        }

        // ---- PV ----
        int s0 = (32 * q + c) & 63;
        int s1 = (32 * q + 16 + c) & 63;
        int v0 = 32 * (q & 1) + c;
        int v1 = v0 + 16;
        bool hi = (q >= 2);                 // k >= 16 -> zero pad
        {
            int a0 = __shfl((int)pa0, s0);
            int a1 = __shfl((int)pa1, s0);
            int a2 = __shfl((int)pa0, s1);
            int a3 = __shfl((int)pa1, s1);
            uint4 A2u;
            A2u.x = hi ? 0u : (unsigned)a0;
            A2u.y = hi ? 0u : (unsigned)a1;
            A2u.z = hi ? 0u : (unsigned)a2;
            A2u.w = hi ? 0u : (unsigned)a3;
            bf16x8 A2 = __builtin_bit_cast(bf16x8, A2u);

            unsigned short* Ot = qkls[w][0];   // Q tile done being read
            #pragma unroll
            for (int nb = 0; nb < 4; ++nb) {
                uint4 B2u;
                B2u.x = (unsigned)__shfl((int)pkV[nb].x, v0);
                B2u.y = (unsigned)__shfl((int)pkV[nb].y, v0);
                B2u.z = (unsigned)__shfl((int)pkV[nb].x, v1);
                B2u.w = (unsigned)__shfl((int)pkV[nb].y, v1);
                bf16x8 B2 = __builtin_bit_cast(bf16x8, B2u);
                f32x4 o = (f32x4){0.f, 0.f, 0.f, 0.f};
                o = __builtin_amdgcn_mfma_f32_16x16x32_bf16(A2, B2, o, 0, 0, 0);
                unsigned u01 = pack2(o[0], o[1]);
                unsigned u23 = pack2(o[2], o[3]);
                int base = 4 * q * 72 + nb * 16 + c;
                Ot[base]       = (unsigned short)u01;
                Ot[base + 72]  = (unsigned short)(u01 >> 16);
                Ot[base + 144] = (unsigned short)u23;
                Ot[base + 216] = (unsigned short)(u23 >> 16);
            }
        }

        // ---- coalesced stores: lane l covers row l>>2, 16 cols ----
        {
            int gi = (waveTok0 >> 4) + g;
            int b    = gi >> 9;
            int grem = gi & 511;
            int rowbase = b * 512 + (grem >> 4);
            int colpref = (grem & 15) * 64;
            const unsigned short* osrc = qkls[w][0] + (l >> 2) * 72 + (l & 3) * 16;
            uint4 ov0 = *(const uint4*)(osrc);
            uint4 ov1 = *(const uint4*)(osrc + 8);
            unsigned short* dst = out2 + (size_t)(rowbase + (l >> 2) * 32) * 1024
                                       + colpref + (l & 3) * 16;
            *(uint4*)(dst)     = ov0;
            *(uint4*)(dst + 8) = ov1;
        }
    }
}

// ---------------------------------------------------------------------------
// K2: C[16384][1024] = out2 @ Wo^T + bo  (bf16 MFMA, fp32 acc/out)
// 256x256 tile, BK=64, 512 threads (8 waves, 2Mx4N). One barrier per K-tile;
// waves free-run within a tile. B = Wo pre-packed fragment-linear (one
// coalesced 16B/lane L2 load per frag, no LDS); A triple-buffered LDS staged
// 2 tiles ahead via global_load_lds; counted vmcnt(4) keeps A prefetch alive.
// (Unchanged this round to get a clean top-5 measurement next to fixed k_fused.)
// ---------------------------------------------------------------------------
#define STG(gb, lb, half, kt) do { \
    gload_lds16((gb) + (size_t)(half) * 131072 + (size_t)(kt) * 64 + ga0, \
                (lb) + (half) * 8192 + lo0); \
    gload_lds16((gb) + (size_t)(half) * 131072 + (size_t)(kt) * 64 + ga1, \
                (lb) + (half) * 8192 + lo1); \
} while (0)

#define LDA4(buf, mh) do { \
    _Pragma("unroll") \
    for (int i2 = 0; i2 < 4; ++i2) { \
        const unsigned short* _p = (buf) + (wrow + ((mh) * 4 + i2) * 16 + lm) * 64; \
        a[i2][0] = *(const bf16x8*)(_p + jo0); \
        a[i2][1] = *(const bf16x8*)(_p + jo1); \
    } \
} while (0)

// next tile's B-frags: 8 x global dwordx4, 16B/lane, L2-hot
#define GLBB(d, gp) do { \
    _Pragma("unroll") \
    for (int n = 0; n < 4; ++n) { \
        d[n][0] = *(const bf16x8*)((gp) + n * 512); \
        d[n][1] = *(const bf16x8*)((gp) + 32768 + n * 512); \
    } \
} while (0)

// 32 MFMAs: one M-half (4 row-frags) x full N (4 col-frags) x K=64 (2 chained)
#define MM16(mh, B) do { \
    _Pragma("unroll") \
    for (int i2 = 0; i2 < 4; ++i2) { \
        _Pragma("unroll") \
        for (int n = 0; n < 4; ++n) { \
            acc[(mh)*4+i2][n] = __builtin_amdgcn_mfma_f32_16x16x32_bf16( \
                a[i2][0], B[n][0], acc[(mh)*4+i2][n], 0, 0, 0); \
            acc[(mh)*4+i2][n] = __builtin_amdgcn_mfma_f32_16x16x32_bf16( \
                a[i2][1], B[n][1], acc[(mh)*4+i2][n], 0, 0, 0); \
        } \
    } \
} while (0)

#define TILE(_t, cB, nB) do { \
    if ((_t) < 15) GLBB(nB, gB); \
    if ((_t) < 14) { STG(Ab, pAs, 0, (_t) + 2); STG(Ab, pAs, 1, (_t) + 2); } \
    LDA4(pAr, 0); \
    asm volatile("s_waitcnt lgkmcnt(0)" ::: "memory"); \
    __builtin_amdgcn_sched_barrier(0); \
    __builtin_amdgcn_s_setprio(1); \
    MM16(0, cB); \
    __builtin_amdgcn_s_setprio(0); \
    LDA4(pAr, 1); \
    asm volatile("s_waitcnt lgkmcnt(0)" ::: "memory"); \
    __builtin_amdgcn_sched_barrier(0); \
    __builtin_amdgcn_s_setprio(1); \
    MM16(1, cB); \
    __builtin_amdgcn_s_setprio(0); \
    if ((_t) < 14)       { asm volatile("s_waitcnt vmcnt(4)" ::: "memory"); } \
    else if ((_t) == 14) { asm volatile("s_waitcnt vmcnt(0)" ::: "memory"); } \
    __builtin_amdgcn_s_barrier(); \
    { unsigned short* _tmp = pAr; pAr = pAn; pAn = pAs; pAs = _tmp; } \
    gB += 65536; \
} while (0)

__global__ __launch_bounds__(512, 2) void k_gemm256(const unsigned short* __restrict__ A,
                                                    const unsigned short* __restrict__ Bp,
                                                    const float* __restrict__ bias,
                                                    float* __restrict__ C) {
    extern __shared__ __align__(16) unsigned short lds[];
    unsigned short* As0 = lds;                 // [256][64] bf16
    unsigned short* As1 = lds + 16384;
    unsigned short* As2 = lds + 32768;         // 96 KiB total, A only

    const int t = threadIdx.x;
    const int w = t >> 6, l = t & 63;
    const int lm = l & 15, q4 = l >> 4;
    const int jxor = lm & 7;
    const int jo0 = ((0 + q4) ^ jxor) * 8;     // kc=0 chunk (swizzled)
    const int jo1 = ((4 + q4) ^ jxor) * 8;     // kc=1 chunk (swizzled)

    // bijective XCD swizzle (nwg = 256, divisible by 8)
    const int bid = blockIdx.x;
    const int wg  = (bid & 7) * 32 + (bid >> 3);
    const int m0  = (wg >> 2) * 256;
    const int n0  = (wg & 3) * 256;

    const int wrow = (w >> 2) * 128;           // wave's M offset in tile
    const int wcol = (w & 3) * 64;             // wave's N offset in tile

    // A staging slots: s = w*128 + {l, l+64} cover 1024 x 16B chunks/half-tile
    const int s1 = w * 128 + l;
    const int s2 = s1 + 64;
    const int r0 = s1 >> 3, c0 = s1 & 7;
    const int r1 = s2 >> 3, c1 = s2 & 7;
    const size_t ga0 = (size_t)r0 * 1024 + (size_t)((c0 ^ (r0 & 7)) * 8);
    const size_t ga1 = (size_t)r1 * 1024 + (size_t)((c1 ^ (r1 & 7)) * 8);
    const int lo0 = s1 * 8;
    const int lo1 = s2 * 8;

    const unsigned short* Ab = A + (size_t)m0 * 1024;
    // fragment-linear B base: this wave's 4 n-blocks, this lane's 16B
    const unsigned short* gB = Bp + (size_t)((n0 >> 4) + (wcol >> 4)) * 512
                                  + (size_t)l * 8;

    f32x4 acc[8][4];
    #pragma unroll
    for (int mi = 0; mi < 8; ++mi)
        #pragma unroll
        for (int ni = 0; ni < 4; ++ni)
            acc[mi][ni] = (f32x4){0.f, 0.f, 0.f, 0.f};

    unsigned short* pAr = As0;   // A(t)   read
    unsigned short* pAn = As1;   // A(t+1)
    unsigned short* pAs = As2;   // A(t+2) stage target

    bf16x8 a[4][2];
    bf16x8 bC[4][2], bN[4][2];

    // ---- prologue: B(0) first (oldest), then A0, A1 ----
    GLBB(bC, gB);
    STG(Ab, pAr, 0, 0); STG(Ab, pAr, 1, 0);
    STG(Ab, pAn, 0, 1); STG(Ab, pAn, 1, 1);
    asm volatile("s_waitcnt vmcnt(4)" ::: "memory");   // B0 + A0 landed, A1 in flight
    __builtin_amdgcn_s_barrier();
    gB += 65536;                                        // point at tile 1

    #pragma unroll 1
    for (int tt = 0; tt < 8; ++tt) {
        TILE(2 * tt,     bC, bN);
        TILE(2 * tt + 1, bN, bC);
    }

    // ---- epilogue: bias + fp32 stores, 4 consecutive 64B bursts per (mi,r)
    float bc[4];
    #pragma unroll
    for (int ni = 0; ni < 4; ++ni) bc[ni] = bias[n0 + wcol + ni * 16 + lm];
    #pragma unroll
    for (int mi = 0; mi < 8; ++mi) {
        #pragma unroll
        for (int r = 0; r < 4; ++r) {
            const int row = m0 + wrow + mi * 16 + q4 * 4 + r;
            float* cp = C + (size_t)row * 1024 + n0 + wcol + lm;
            #pragma unroll
            for (int ni = 0; ni < 4; ++ni)
                cp[ni * 16] = acc[mi][ni][r] + bc[ni];
        }
    }
}

// ---------------------------------------------------------------------------
extern "C" void kernel_launch(void* const* d_in, const int* in_sizes, int n_in,
                              void* d_out, int out_size, void* d_ws, size_t ws_size,
                              hipStream_t stream) {
    const float* x  = (const float*)d_in[0];
    const float* wq = (const float*)d_in[1];
    const float* wk = (const float*)d_in[2];
    const float* wv = (const float*)d_in[3];
    const float* wo = (const float*)d_in[4];
    const float* bo = (const float*)d_in[5];
    float* out = (float*)d_out;

    unsigned short* out2  = (unsigned short*)d_ws;           // 16384*1024 bf16 (32 MB)
    unsigned short* wob   = out2 + (size_t)NGRP * 1024;      // 1024*1024 bf16 packed (2 MB)
    unsigned short* wqkvb = wob + (size_t)EMB * EMB;         // 3*4096 bf16 (24 KB)

    static int s_once = []() {
        hipFuncSetAttribute((const void*)k_gemm256,
                            hipFuncAttributeMaxDynamicSharedMemorySize, 98304);
        return 0;
    }();
    (void)s_once;

    k_cvt    <<<524,  256, 0, stream>>>(wo, wq, wk, wv, wob, wqkvb);
    k_fused  <<<2048, 256, 0, stream>>>(x, wqkvb, out2);
    k_gemm256<<<256, 512, 98304, stream>>>(out2, wob, bo, out);
}

// Round 6
// 150.252 us; speedup vs baseline: 1.7315x; 1.2387x over previous
//
#include <hip/hip_runtime.h>
#include <hip/hip_bf16.h>
#include <stdint.h>

// Problem constants
#define TOKS   262144      // B*S = 32*8192
#define NGRP   16384       // B*G = 32*512
#define EMB    1024
#define HD     64

using bf16x8 = __attribute__((ext_vector_type(8))) short;   // 8 bf16 (4 VGPRs) MFMA operand
using f32x4  = __attribute__((ext_vector_type(4))) float;   // MFMA accumulator

__device__ __forceinline__ unsigned pack2(float a, float b) {
    union { __hip_bfloat162 h; unsigned u; } cvt;
    cvt.h = __float22bfloat162_rn(make_float2(a, b));   // RNE pk-convert
    return cvt.u;
}
__device__ __forceinline__ bf16x8 cvt8(float4 v0, float4 v1) {
    uint4 u;
    u.x = pack2(v0.x, v0.y);
    u.y = pack2(v0.z, v0.w);
    u.z = pack2(v1.x, v1.y);
    u.w = pack2(v1.z, v1.w);
    return __builtin_bit_cast(bf16x8, u);
}

// ---------------------------------------------------------------------------
// K0: pack Wo (fp32 [1024][1024]) into MFMA-fragment-linear bf16 (blocks 0..511):
//       packed[((kc*64 + nb)*64 + l)*8 + e] = bf16(Wo[nb*16 + (l&15)][kc*32 + (l>>4)*8 + e])
//     Wq|Wk|Wv (fp32 [64][64]) -> bf16 packed [3][4096] (blocks 512..523).
// ---------------------------------------------------------------------------
__global__ __launch_bounds__(256) void k_cvt(const float* __restrict__ wo,
                                             const float* __restrict__ wq,
                                             const float* __restrict__ wk,
                                             const float* __restrict__ wv,
                                             unsigned short* __restrict__ wob,
                                             unsigned short* __restrict__ wqkvb) {
    int bid = blockIdx.x;
    if (bid < 512) {
        int tid = bid * 256 + threadIdx.x;   // 0..131071, 8 elems each
        int kc  = tid >> 12;                 // k-chunk of 32, 0..31
        int nb  = (tid >> 6) & 63;           // n-block of 16
        int l   = tid & 63;                  // lane within fragment
        int n   = nb * 16 + (l & 15);
        int k   = kc * 32 + (l >> 4) * 8;
        const float* src = wo + (size_t)n * 1024 + k;
        float4 v0 = *(const float4*)(src);
        float4 v1 = *(const float4*)(src + 4);
        *(bf16x8*)(wob + (size_t)tid * 8) = cvt8(v0, v1);
    } else {
        int b = bid - 512;                  // 0..11
        int m = b >> 2;
        const float* src = (m == 0) ? wq : ((m == 1) ? wk : wv);
        int idx = ((b & 3) * 256 + threadIdx.x) * 4;
        float4 v = *(const float4*)(src + idx);
        uint2 p;
        p.x = pack2(v.x, v.y);
        p.y = pack2(v.z, v.w);
        *(uint2*)(wqkvb + m * 4096 + idx) = p;
    }
}

// ---------------------------------------------------------------------------
// K1 (MEGA): fully fused attention + output GEMM. Grid 256 blocks x 512 thr.
// Block (batch = bid>>3, q8 = bid&7) owns 1024 contiguous tokens
// [bid*1024, +1024) = 64 groups, whose attention outputs form EXACTLY 64
// complete rows of the out2 matrix: local row lr = h*4 + gbq (h = token%16,
// gbq = local group-block), local col = (g%16)*64 + d. Those rows live ONLY
// in LDS (A-tile, 128 KB), then the block computes C[64 rows][1024] =
// A @ Wo^T + bias directly. out2 never touches HBM (-64 MB traffic), the
// GEMM K-loop has NO barriers and NO staging (A resident in LDS, B = Wo
// register-streamed from the fragment-packed wob, L2-resident).
//
// LDS swizzle (uniform, both write & read sides): physical_col =
// logical_col ^ ((row & 7) << 3) on the [64][1024] A-tile and on the
// per-wave K-scratch. Makes both the energy ds_read_b128 (rows = c) and the
// GEMM A-frag ds_read_b128 (rows = m*16+lm) conflict-free (G4).
//
// Phase 1 (attention): 8 waves x 8 sequential groups (round-5 verified
// numerics). Q-tile is staged in the group's OWN output stripe (dead after
// the energy MFMA, overwritten by PV output). K-tile in 2KB/wave scratch.
// Phase 2 (GEMM): one __syncthreads, then each wave computes M=64 x N=128:
// 4 m-frags x 8 n-frags x 32 kc = 1024 MFMA, kc ascending (bit-identical
// accumulation order to the round-2..5 verified GEMM). B even/odd register
// double-buffer; compiler inserts counted vmcnt/lgkmcnt.
// ---------------------------------------------------------------------------
#define SCL 0.0450842200278f   /* log2(e)/32 */

#define MFMA_B16(A, B, Cc) __builtin_amdgcn_mfma_f32_16x16x32_bf16(A, B, Cc, 0, 0, 0)

__global__ __launch_bounds__(512, 2) void k_mega(const float* __restrict__ x,
                                                 const unsigned short* __restrict__ wqkv,
                                                 const unsigned short* __restrict__ wob,
                                                 const float* __restrict__ bias,
                                                 float* __restrict__ C) {
    extern __shared__ __align__(16) unsigned short lds[];
    unsigned short* out2s = lds;               // [64][1024] bf16 A-tile (128 KB)
    unsigned short* kscr  = lds + 65536;       // [8 waves][16][64] K-scratch (16 KB)

    const int t = threadIdx.x;
    const int w = t >> 6, l = t & 63;
    const int c = l & 15, q = l >> 4;
    const int bid   = blockIdx.x;
    const int batch = bid >> 3, q8 = bid & 7;
    unsigned short* kw = kscr + w * 1024;

    // ================= phase 1: attention (8 groups/wave, sequential) =====
    #pragma unroll 1
    for (int i = 0; i < 8; ++i) {
        const int gl   = w * 8 + i;            // local group 0..63
        const int gbq  = gl >> 4;              // local gb 0..3
        const int gcol = gl & 15;              // column stripe
        const size_t tok0 = (size_t)bid * 1024 + (size_t)gl * 16;

        // ---- x A-frags (fp32 -> bf16 in-register) ----
        bf16x8 xa[2];
        {
            const float* xp = x + (tok0 + c) * 64 + q * 8;
            #pragma unroll
            for (int kc = 0; kc < 2; ++kc) {
                float4 v0 = *(const float4*)(xp + kc * 32);
                float4 v1 = *(const float4*)(xp + kc * 32 + 4);
                xa[kc] = cvt8(v0, v1);
            }
        }

        // Q/O stripe base: rows 16q+gbq (+4,+8,+12), masks alternate even/odd token
        const int mQ0 = gbq << 3;              // (row&7)<<3 for tokens 4q+0, 4q+2
        const int mQ1 = 32 + (gbq << 3);       // for tokens 4q+1, 4q+3
        unsigned short* qslot = out2s + (size_t)(16 * q + gbq) * 1024 + gcol * 64;

        // ---- projections: Q -> A-tile stripe, K -> scratch, V -> regs ----
        uint2 pkV[4];
        #pragma unroll
        for (int m = 0; m < 3; ++m) {
            #pragma unroll
            for (int nb = 0; nb < 4; ++nb) {
                const unsigned short* wp = wqkv + m * 4096 + (nb * 16 + c) * 64 + q * 8;
                bf16x8 w0 = *(const bf16x8*)(wp);
                bf16x8 w1 = *(const bf16x8*)(wp + 32);
                f32x4 acc = (f32x4){0.f, 0.f, 0.f, 0.f};
                acc = MFMA_B16(xa[0], w0, acc);
                acc = MFMA_B16(xa[1], w1, acc);
                unsigned u01 = pack2(acc[0], acc[1]);
                unsigned u23 = pack2(acc[2], acc[3]);
                const int d = nb * 16 + c;
                if (m == 0) {
                    qslot[(d ^ mQ0)]              = (unsigned short)u01;
                    qslot[4 * 1024 + (d ^ mQ1)]   = (unsigned short)(u01 >> 16);
                    qslot[8 * 1024 + (d ^ mQ0)]   = (unsigned short)u23;
                    qslot[12 * 1024 + (d ^ mQ1)]  = (unsigned short)(u23 >> 16);
                } else if (m == 1) {
                    const int kr = 4 * q;
                    kw[(kr + 0) * 64 + (d ^ (((kr + 0) & 7) << 3))] = (unsigned short)u01;
                    kw[(kr + 1) * 64 + (d ^ (((kr + 1) & 7) << 3))] = (unsigned short)(u01 >> 16);
                    kw[(kr + 2) * 64 + (d ^ (((kr + 2) & 7) << 3))] = (unsigned short)u23;
                    kw[(kr + 3) * 64 + (d ^ (((kr + 3) & 7) << 3))] = (unsigned short)(u23 >> 16);
                } else {
                    pkV[nb].x = u01;    // tokens 4q+0,1
                    pkV[nb].y = u23;    // tokens 4q+2,3
                }
            }
        }

        // ---- energy^T[j][i]: A = K-frag (scratch), B = Q-frag (A-tile) ----
        f32x4 e = (f32x4){0.f, 0.f, 0.f, 0.f};
        {
            const int mq = ((c * 4 + gbq) & 7) << 3;
            const unsigned short* qrow = out2s + (size_t)(c * 4 + gbq) * 1024 + gcol * 64;
            #pragma unroll
            for (int kc = 0; kc < 2; ++kc) {
                const int L = kc * 32 + q * 8;
                bf16x8 ka = *(const bf16x8*)(kw + c * 64 + (L ^ ((c & 7) << 3)));
                bf16x8 qb = *(const bf16x8*)(qrow + (L ^ mq));
                e = MFMA_B16(ka, qb, e);
            }
        }
        // lane(q,c): e[r] = energy[i=c][j=4q+r]

        // ---- softmax over j ----
        unsigned pa0, pa1;
        {
            float mx = fmaxf(fmaxf(e[0], e[1]), fmaxf(e[2], e[3]));
            mx = fmaxf(mx, __shfl_xor(mx, 16));
            mx = fmaxf(mx, __shfl_xor(mx, 32));
            float p0 = exp2f((e[0] - mx) * SCL);
            float p1 = exp2f((e[1] - mx) * SCL);
            float p2 = exp2f((e[2] - mx) * SCL);
            float p3 = exp2f((e[3] - mx) * SCL);
            float s = p0 + p1 + p2 + p3;
            s += __shfl_xor(s, 16);
            s += __shfl_xor(s, 32);
            float rinv = 1.0f / s;
            pa0 = pack2(p0 * rinv, p1 * rinv);   // j = 4q+0,1
            pa1 = pack2(p2 * rinv, p3 * rinv);   // j = 4q+2,3
        }

        // ---- PV: output overwrites the Q stripe (Q dead after energy) ----
        {
            const int sh0 = (32 * q + c) & 63;
            const int sh1 = (32 * q + 16 + c) & 63;
            const int sv0 = 32 * (q & 1) + c;
            const int sv1 = sv0 + 16;
            const bool hi = (q >= 2);           // k >= 16 -> zero pad
            int a0 = __shfl((int)pa0, sh0);
            int a1 = __shfl((int)pa1, sh0);
            int a2 = __shfl((int)pa0, sh1);
            int a3 = __shfl((int)pa1, sh1);
            uint4 A2u;
            A2u.x = hi ? 0u : (unsigned)a0;
            A2u.y = hi ? 0u : (unsigned)a1;
            A2u.z = hi ? 0u : (unsigned)a2;
            A2u.w = hi ? 0u : (unsigned)a3;
            bf16x8 A2 = __builtin_bit_cast(bf16x8, A2u);

            #pragma unroll
            for (int nb = 0; nb < 4; ++nb) {
                uint4 B2u;
                B2u.x = (unsigned)__shfl((int)pkV[nb].x, sv0);
                B2u.y = (unsigned)__shfl((int)pkV[nb].y, sv0);
                B2u.z = (unsigned)__shfl((int)pkV[nb].x, sv1);
                B2u.w = (unsigned)__shfl((int)pkV[nb].y, sv1);
                bf16x8 B2 = __builtin_bit_cast(bf16x8, B2u);
                f32x4 o = (f32x4){0.f, 0.f, 0.f, 0.f};
                o = MFMA_B16(A2, B2, o);
                unsigned u01 = pack2(o[0], o[1]);
                unsigned u23 = pack2(o[2], o[3]);
                const int d = nb * 16 + c;
                qslot[(d ^ mQ0)]              = (unsigned short)u01;
                qslot[4 * 1024 + (d ^ mQ1)]   = (unsigned short)(u01 >> 16);
                qslot[8 * 1024 + (d ^ mQ0)]   = (unsigned short)u23;
                qslot[12 * 1024 + (d ^ mQ1)]  = (unsigned short)(u23 >> 16);
            }
        }
    }

    __syncthreads();   // A-tile complete

    // ================= phase 2: GEMM  C[64][1024] = A @ Wo^T + bias =======
    // wave w: all 64 rows x cols [w*128, w*128+128). No barriers, no staging.
    const unsigned short* gBw = wob + (size_t)(w * 8) * 512 + (size_t)l * 8;
    float bc[8];
    #pragma unroll
    for (int nb = 0; nb < 8; ++nb) bc[nb] = bias[w * 128 + nb * 16 + c];

    f32x4 acc[4][8];
    #pragma unroll
    for (int m = 0; m < 4; ++m)
        #pragma unroll
        for (int nb = 0; nb < 8; ++nb)
            acc[m][nb] = (f32x4){0.f, 0.f, 0.f, 0.f};

    const int axor = (c & 7) << 3;             // A-frag swizzle: rows m*16+c -> (row&7)=c&7
    bf16x8 bE[8], bO[8], a[4];

    #pragma unroll
    for (int nb = 0; nb < 8; ++nb) bE[nb] = *(const bf16x8*)(gBw + nb * 512);   // kc=0

    #pragma unroll 1
    for (int tt = 0; tt < 16; ++tt) {
        const size_t kb = (size_t)tt * 65536;
        #pragma unroll
        for (int nb = 0; nb < 8; ++nb)          // prefetch odd kc = 2tt+1
            bO[nb] = *(const bf16x8*)(gBw + kb + 32768 + nb * 512);
        {
            const int L = (2 * tt) * 32 + q * 8;
            #pragma unroll
            for (int m = 0; m < 4; ++m)
                a[m] = *(const bf16x8*)(out2s + (size_t)(m * 16 + c) * 1024 + (L ^ axor));
            #pragma unroll
            for (int m = 0; m < 4; ++m)
                #pragma unroll
                for (int nb = 0; nb < 8; ++nb)
                    acc[m][nb] = MFMA_B16(a[m], bE[nb], acc[m][nb]);
        }
        if (tt < 15) {
            #pragma unroll
            for (int nb = 0; nb < 8; ++nb)      // prefetch even kc = 2tt+2
                bE[nb] = *(const bf16x8*)(gBw + kb + 65536 + nb * 512);
        }
        {
            const int L = (2 * tt + 1) * 32 + q * 8;
            #pragma unroll
            for (int m = 0; m < 4; ++m)
                a[m] = *(const bf16x8*)(out2s + (size_t)(m * 16 + c) * 1024 + (L ^ axor));
            #pragma unroll
            for (int m = 0; m < 4; ++m)
                #pragma unroll
                for (int nb = 0; nb < 8; ++nb)
                    acc[m][nb] = MFMA_B16(a[m], bO[nb], acc[m][nb]);
        }
    }

    // ---- epilogue: bias + fp32 store. Global C row for local row lr =
    // m*16 + q*4 + r:  rg = batch*512 + (lr>>2)*32 + q8*4 + (lr&3).
    #pragma unroll
    for (int m = 0; m < 4; ++m) {
        #pragma unroll
        for (int r = 0; r < 4; ++r) {
            const int rg = batch * 512 + (m * 4 + q) * 32 + q8 * 4 + r;
            float* cp = C + (size_t)rg * 1024 + w * 128 + c;
            #pragma unroll
            for (int nb = 0; nb < 8; ++nb)
                cp[nb * 16] = acc[m][nb][r] + bc[nb];
        }
    }
}

// ---------------------------------------------------------------------------
extern "C" void kernel_launch(void* const* d_in, const int* in_sizes, int n_in,
                              void* d_out, int out_size, void* d_ws, size_t ws_size,
                              hipStream_t stream) {
    const float* x  = (const float*)d_in[0];
    const float* wq = (const float*)d_in[1];
    const float* wk = (const float*)d_in[2];
    const float* wv = (const float*)d_in[3];
    const float* wo = (const float*)d_in[4];
    const float* bo = (const float*)d_in[5];
    float* out = (float*)d_out;

    unsigned short* wob   = (unsigned short*)d_ws;           // 1024*1024 bf16 packed (2 MB)
    unsigned short* wqkvb = wob + (size_t)EMB * EMB;         // 3*4096 bf16 (24 KB)

    static int s_once = []() {
        hipFuncSetAttribute((const void*)k_mega,
                            hipFuncAttributeMaxDynamicSharedMemorySize, 147456);
        return 0;
    }();
    (void)s_once;

    k_cvt <<<524, 256, 0, stream>>>(wo, wq, wk, wv, wob, wqkvb);
    k_mega<<<256, 512, 147456, stream>>>(x, wqkvb, wob, bo, out);
}